// Round 8
// baseline (318.377 us; speedup 1.0000x reference)
//
#include <hip/hip_runtime.h>
#include <math.h>

// Problem constants
#define QDIM 512     // 2^9 state dim
#define DD   128     // K*C_IN = input dim of quadratic form
#define LIN  4096
#define LOUT 4089    // (4096 - 7 - 1)/1 + 1
#define NC   16      // C_IN
#define NB   16      // batch
#define PRE_BLOCKS 512

// Scratch in device globals (NOT d_ws) — R5 lesson. Every data element is
// rewritten each call before being read -> no cross-call state. Barrier
// state is control-only: cnt self-resets to 0 each barrier, gen is
// monotonic (sense-reversing) -> works across graph replays.
__device__ float g_B[QDIM * DD];
__device__ float g_C[QDIM * DD];
__device__ float g_Q[DD * DD];
__device__ unsigned g_bar_cnt = 0u;
__device__ unsigned g_bar_gen = 0u;

// Device-scope grid barrier (sense-reversing). Requires all PRE_BLOCKS
// co-resident: 512 blocks at __launch_bounds__(256,4) -> >=4 blocks/CU
// capacity (VGPR<=128, LDS ~5KB) x 256 CUs = 1024 slots, 2x slack.
__device__ __forceinline__ void grid_barrier() {
  __syncthreads();
  if (threadIdx.x == 0) {
    __threadfence();   // release prior writes to device scope (L2 wb)
    unsigned gen = __hip_atomic_load(&g_bar_gen, __ATOMIC_RELAXED,
                                     __HIP_MEMORY_SCOPE_AGENT);
    unsigned prev = __hip_atomic_fetch_add(&g_bar_cnt, 1u, __ATOMIC_ACQ_REL,
                                           __HIP_MEMORY_SCOPE_AGENT);
    if (prev == PRE_BLOCKS - 1u) {
      __hip_atomic_store(&g_bar_cnt, 0u, __ATOMIC_RELAXED,
                         __HIP_MEMORY_SCOPE_AGENT);
      __hip_atomic_store(&g_bar_gen, gen + 1u, __ATOMIC_RELEASE,
                         __HIP_MEMORY_SCOPE_AGENT);
    } else {
      while (__hip_atomic_load(&g_bar_gen, __ATOMIC_ACQUIRE,
                               __HIP_MEMORY_SCOPE_AGENT) == gen) {
        __builtin_amdgcn_s_sleep(32);
      }
    }
    __threadfence();   // acquire: invalidate stale cached lines
  }
  __syncthreads();
}

// ---------------------------------------------------------------------------
// Precompute (single persistent kernel). A = (E*R3*E*R2*E*R1)[:, :128].
// Row i of E*R*W equals (R^T e_i)^T W: apply transposed butterflies
// ( [[c,s],[-s,c]] ) in REVERSE qubit order to the E-row in LDS.
// Then Q = A^T S A, S = diag(+1 x256, -1 x256).
// ---------------------------------------------------------------------------

__device__ __forceinline__ void butterfly_T(float* col, const float* theta,
                                            int l, int p) {
  #pragma unroll
  for (int qq = 0; qq < 9; ++qq) {
    int q = 8 - qq;                    // reverse order for transpose
    float half = theta[l * 9 + q] * 0.5f;
    float c = cosf(half), s = sinf(half);
    int right = QDIM >> (q + 1);
    int a = p >> (8 - q);
    int r = p & (right - 1);
    int i0 = (a * 2) * right + r;
    int i1 = i0 + right;
    float v0 = col[i0], v1 = col[i1];
    col[i0] = c * v0 + s * v1;         // transposed 2x2
    col[i1] = c * v1 - s * v0;
    __syncthreads();
  }
}

__global__ __launch_bounds__(256, 4) void precompute_kernel(
    const float* __restrict__ E, const float* __restrict__ theta) {
  __shared__ float erow[QDIM];
  __shared__ float part[DD];
  __shared__ float colA[QDIM];
  int bid = blockIdx.x;                // 0..511
  int tid = threadIdx.x;

  // ---- Phase 1: W1[i][j] = (R1^T e_i)[j], j<128  -> g_B ----
  {
    int i = bid;
    erow[tid]       = E[i * QDIM + tid];
    erow[tid + 256] = E[i * QDIM + tid + 256];
    __syncthreads();
    butterfly_T(erow, theta, 0, tid);
    if (tid < DD) g_B[i * DD + tid] = erow[tid];
  }
  grid_barrier();

  // ---- Phase 2: mm l=1: g_C[i][:] = (R2^T e_i)^T * g_B ----
  {
    int i = bid;
    erow[tid]       = E[i * QDIM + tid];
    erow[tid + 256] = E[i * QDIM + tid + 256];
    __syncthreads();
    butterfly_T(erow, theta, 1, tid);
    int j = tid & 127, h = tid >> 7;
    float a0 = 0.f, a1 = 0.f, a2 = 0.f, a3 = 0.f;
    int m0 = h * 256;
    #pragma unroll 8
    for (int m = m0; m < m0 + 256; m += 4) {
      a0 = fmaf(erow[m + 0], g_B[(m + 0) * DD + j], a0);
      a1 = fmaf(erow[m + 1], g_B[(m + 1) * DD + j], a1);
      a2 = fmaf(erow[m + 2], g_B[(m + 2) * DD + j], a2);
      a3 = fmaf(erow[m + 3], g_B[(m + 3) * DD + j], a3);
    }
    float sum = (a0 + a1) + (a2 + a3);
    if (h == 1) part[j] = sum;
    __syncthreads();
    if (h == 0) g_C[i * DD + j] = sum + part[j];
  }
  grid_barrier();

  // ---- Phase 3: mm l=2: g_B[i][:] = (R3^T e_i)^T * g_C ----
  {
    int i = bid;
    erow[tid]       = E[i * QDIM + tid];
    erow[tid + 256] = E[i * QDIM + tid + 256];
    __syncthreads();
    butterfly_T(erow, theta, 2, tid);
    int j = tid & 127, h = tid >> 7;
    float a0 = 0.f, a1 = 0.f, a2 = 0.f, a3 = 0.f;
    int m0 = h * 256;
    #pragma unroll 8
    for (int m = m0; m < m0 + 256; m += 4) {
      a0 = fmaf(erow[m + 0], g_C[(m + 0) * DD + j], a0);
      a1 = fmaf(erow[m + 1], g_C[(m + 1) * DD + j], a1);
      a2 = fmaf(erow[m + 2], g_C[(m + 2) * DD + j], a2);
      a3 = fmaf(erow[m + 3], g_C[(m + 3) * DD + j], a3);
    }
    float sum = (a0 + a1) + (a2 + a3);
    if (h == 1) part[j] = sum;
    __syncthreads();
    if (h == 0) g_B[i * DD + j] = sum + part[j];
  }
  grid_barrier();

  // ---- Phase 4: g_Q[j1][j2] = sum_i sgn(i) A[i][j1] A[i][j2], A = g_B ----
  if (bid < DD) {
    int j1 = bid;
    for (int i = tid; i < QDIM; i += 256) {
      float sgn = (i < 256) ? 1.0f : -1.0f;
      colA[i] = sgn * g_B[i * DD + j1];
    }
    __syncthreads();
    int j2 = tid & 127, h = tid >> 7;
    float a0 = 0.f, a1 = 0.f, a2 = 0.f, a3 = 0.f;
    int i0 = h * 256;
    #pragma unroll 8
    for (int i = i0; i < i0 + 256; i += 4) {
      a0 = fmaf(colA[i + 0], g_B[(i + 0) * DD + j2], a0);
      a1 = fmaf(colA[i + 1], g_B[(i + 1) * DD + j2], a1);
      a2 = fmaf(colA[i + 2], g_B[(i + 2) * DD + j2], a2);
      a3 = fmaf(colA[i + 3], g_B[(i + 3) * DD + j2], a3);
    }
    float sum = (a0 + a1) + (a2 + a3);
    if (h == 1) part[j2] = sum;
    __syncthreads();
    if (h == 0) g_Q[j1 * DD + j2] = sum + part[j2];
  }
}

// ---------------------------------------------------------------------------
// Main pass (unchanged from R6/R7): out[b,t] = v^T Q v / (v^T v + 1e-12)
// Block = 64 t's x 4 i-chunk waves; wave s owns u[32] for i in [32s,32s+32).
// ---------------------------------------------------------------------------
__global__ __launch_bounds__(256, 4) void quad_kernel(const float* __restrict__ x,
                                                      float* __restrict__ out) {
  __shared__ float xs[NC][72];      // 71 used (64 t + 7 halo)
  __shared__ float pdot[4][64];
  __shared__ float pnrm[4][64];
  int b = blockIdx.x;
  int t0 = blockIdx.y * 64;
  int tid = threadIdx.x;
  int l = tid & 63;
  int s = tid >> 6;
  const float* xb = x + (size_t)b * NC * LIN;

  for (int idx = tid; idx < NC * 71; idx += 256) {
    int c = idx / 71, o = idx % 71;
    int g = t0 + o;
    xs[c][o] = (g < LIN) ? xb[c * LIN + g] : 0.0f;
  }
  __syncthreads();

  int su = __builtin_amdgcn_readfirstlane(s);
  const float* qbase = g_Q + su * 32;

  float u[32];
  #pragma unroll
  for (int i = 0; i < 32; ++i) u[i] = 0.0f;

  #pragma unroll 2
  for (int j = 0; j < 128; ++j) {
    float vj = xs[j >> 3][l + (j & 7)];
    const float4* qr = (const float4*)(qbase + (size_t)j * DD);
    #pragma unroll
    for (int i4 = 0; i4 < 8; ++i4) {
      float4 q4 = qr[i4];
      u[i4 * 4 + 0] = fmaf(q4.x, vj, u[i4 * 4 + 0]);
      u[i4 * 4 + 1] = fmaf(q4.y, vj, u[i4 * 4 + 1]);
      u[i4 * 4 + 2] = fmaf(q4.z, vj, u[i4 * 4 + 2]);
      u[i4 * 4 + 3] = fmaf(q4.w, vj, u[i4 * 4 + 3]);
    }
  }

  float dot = 0.0f, nrm = 0.0f;
  #pragma unroll
  for (int i = 0; i < 32; ++i) {
    int ii = su * 32 + i;
    float vi = xs[ii >> 3][l + (ii & 7)];
    dot = fmaf(vi, u[i], dot);
    nrm = fmaf(vi, vi, nrm);
  }
  pdot[s][l] = dot;
  pnrm[s][l] = nrm;
  __syncthreads();
  if (s == 0) {
    float d = pdot[0][l] + pdot[1][l] + pdot[2][l] + pdot[3][l];
    float n = pnrm[0][l] + pnrm[1][l] + pnrm[2][l] + pnrm[3][l];
    int t = t0 + l;
    if (t < LOUT) out[(size_t)b * LOUT + t] = d / (n + 1e-12f);
  }
}

// ---------------------------------------------------------------------------

extern "C" void kernel_launch(void* const* d_in, const int* in_sizes, int n_in,
                              void* d_out, int out_size, void* d_ws, size_t ws_size,
                              hipStream_t stream) {
  const float* x     = (const float*)d_in[0];   // (16,16,4096) f32
  const float* E     = (const float*)d_in[1];   // (512,512)    f32
  const float* theta = (const float*)d_in[2];   // (3,9)        f32
  float* out = (float*)d_out;                   // (16,1,1,4089) f32
  (void)d_ws; (void)ws_size;

  precompute_kernel<<<PRE_BLOCKS, 256, 0, stream>>>(E, theta);
  quad_kernel<<<dim3(NB, 64), 256, 0, stream>>>(x, out);
}

// Round 9
// 75.337 us; speedup vs baseline: 4.2260x; 4.2260x over previous
//
#include <hip/hip_runtime.h>
#include <math.h>

// Problem constants
#define QDIM 512     // 2^9 state dim
#define DD   128     // K*C_IN = input dim of quadratic form
#define LIN  4096
#define LOUT 4089    // (4096 - 7 - 1)/1 + 1
#define NC   16      // C_IN
#define NB   16      // batch

typedef __attribute__((ext_vector_type(8))) short bf16x8;
typedef __attribute__((ext_vector_type(4))) float f32x4;

// Scratch in device globals (NOT d_ws) — R5 lesson. Every element rewritten
// each call before read -> no cross-call state. R8 lesson: NO persistent-grid
// barriers (512 serialized cross-XCD atomic RMWs ~ 70us per barrier).
__device__ float  g_B[QDIM * DD];
__device__ float  g_C[QDIM * DD];
__device__ unsigned short g_Qh[DD * DD];   // bf16 hi part of Q
__device__ unsigned short g_Ql[DD * DD];   // bf16 residual of Q

// ---- bf16 helpers (RNE) ----
__device__ __forceinline__ unsigned short f2bf(float f) {
  union { float f; unsigned u; } v; v.f = f;
  unsigned u = v.u + 0x7FFFu + ((v.u >> 16) & 1u);
  return (unsigned short)(u >> 16);
}
__device__ __forceinline__ float bf2f(unsigned short h) {
  union { unsigned u; float f; } v; v.u = ((unsigned)h) << 16;
  return v.f;
}

// ---------------------------------------------------------------------------
// Precompute (R7 structure, measured-good). A = (E*R3*E*R2*E*R1)[:, :128].
// Row i of E*R*W equals (R^T e_i)^T W: transposed butterflies in REVERSE
// qubit order on the E-row in LDS. Then Q = A^T S A, stored as bf16 hi/lo.
// ---------------------------------------------------------------------------

__device__ __forceinline__ void butterfly_T(float* col, const float* theta,
                                            int l, int p) {
  #pragma unroll
  for (int qq = 0; qq < 9; ++qq) {
    int q = 8 - qq;                    // reverse order for transpose
    float half = theta[l * 9 + q] * 0.5f;
    float c = cosf(half), s = sinf(half);
    int right = QDIM >> (q + 1);
    int a = p >> (8 - q);
    int r = p & (right - 1);
    int i0 = (a * 2) * right + r;
    int i1 = i0 + right;
    float v0 = col[i0], v1 = col[i1];
    col[i0] = c * v0 + s * v1;         // transposed 2x2
    col[i1] = c * v1 - s * v0;
    __syncthreads();
  }
}

// W1[i][j] = (R1^T e_i)[j], j<128  -> g_B
__global__ __launch_bounds__(256) void w1_kernel(const float* __restrict__ E,
                                                 const float* __restrict__ theta) {
  __shared__ float erow[QDIM];
  int i = blockIdx.x;
  int p = threadIdx.x;
  erow[p]       = E[i * QDIM + p];
  erow[p + 256] = E[i * QDIM + p + 256];
  __syncthreads();
  butterfly_T(erow, theta, 0, p);
  if (p < DD) g_B[i * DD + p] = erow[p];
}

// dst[i][:] = (R_l^T e_i)^T * src.  sel: 0 = g_B->g_C, 1 = g_C->g_B.
__global__ __launch_bounds__(256) void mm_fused_kernel(const float* __restrict__ E,
                                                       const float* __restrict__ theta,
                                                       int l, int sel) {
  const float* W = sel ? g_C : g_B;
  float* D       = sel ? g_B : g_C;
  __shared__ float erow[QDIM];
  __shared__ float part[DD];
  int i = blockIdx.x;
  int tid = threadIdx.x;
  erow[tid]       = E[i * QDIM + tid];
  erow[tid + 256] = E[i * QDIM + tid + 256];
  __syncthreads();
  butterfly_T(erow, theta, l, tid);

  int j = tid & 127, h = tid >> 7;
  float a0 = 0.f, a1 = 0.f, a2 = 0.f, a3 = 0.f;
  int m0 = h * 256;
  #pragma unroll 8
  for (int m = m0; m < m0 + 256; m += 4) {
    a0 = fmaf(erow[m + 0], W[(m + 0) * DD + j], a0);
    a1 = fmaf(erow[m + 1], W[(m + 1) * DD + j], a1);
    a2 = fmaf(erow[m + 2], W[(m + 2) * DD + j], a2);
    a3 = fmaf(erow[m + 3], W[(m + 3) * DD + j], a3);
  }
  float sum = (a0 + a1) + (a2 + a3);
  if (h == 1) part[j] = sum;
  __syncthreads();
  if (h == 0) D[i * DD + j] = sum + part[j];
}

// Q[j1][j2] = sum_i sgn(i) A[i][j1] A[i][j2]; A = g_B. Emit bf16 hi/lo.
__global__ __launch_bounds__(256) void formq_kernel() {
  const float* A = g_B;
  __shared__ float colA[QDIM];
  __shared__ float part[DD];
  int j1 = blockIdx.x;
  int tid = threadIdx.x;
  int j2 = tid & 127, h = tid >> 7;
  for (int i = tid; i < QDIM; i += 256) {
    float sgn = (i < 256) ? 1.0f : -1.0f;
    colA[i] = sgn * A[i * DD + j1];
  }
  __syncthreads();
  float a0 = 0.f, a1 = 0.f, a2 = 0.f, a3 = 0.f;
  int i0 = h * 256;
  #pragma unroll 8
  for (int i = i0; i < i0 + 256; i += 4) {
    a0 = fmaf(colA[i + 0], A[(i + 0) * DD + j2], a0);
    a1 = fmaf(colA[i + 1], A[(i + 1) * DD + j2], a1);
    a2 = fmaf(colA[i + 2], A[(i + 2) * DD + j2], a2);
    a3 = fmaf(colA[i + 3], A[(i + 3) * DD + j2], a3);
  }
  float sum = (a0 + a1) + (a2 + a3);
  if (h == 1) part[j2] = sum;
  __syncthreads();
  if (h == 0) {
    sum += part[j2];
    unsigned short hi = f2bf(sum);
    unsigned short lo = f2bf(sum - bf2f(hi));
    g_Qh[j1 * DD + j2] = hi;
    g_Ql[j1 * DD + j2] = lo;
  }
}

// ---------------------------------------------------------------------------
// Main pass via MFMA split-bf16: U = V*Q with V=v_hi+v_lo, Q=Q_hi+Q_lo,
// keeping Vh*Qh + Vh*Ql + Vl*Qh (dropped Vl*Ql ~ 2^-18 rel).
// Block: 64 t-rows x 4 waves; wave w owns M-tile w (16 rows) x all 128 i.
// A-frag (V): lane = row(lane&15), k = (lane>>4)*8+e  -> 8 consecutive xs.
// B-frag (Q): Q symmetric -> read row (n*16+lane&15), 8 consecutive j.
// C-frag: col=lane&15, row=(lane>>4)*4+reg  [verified m89/m91].
// Epilogue: dot/nrm in f32 from LDS, 16-lane shfl reduce.
// ---------------------------------------------------------------------------
__global__ __launch_bounds__(256, 4) void quad_mfma_kernel(const float* __restrict__ x,
                                                           float* __restrict__ out) {
  __shared__ float xs[NC][72];      // 71 used (64 t + 7 halo)
  int b = blockIdx.x;
  int t0 = blockIdx.y * 64;
  int tid = threadIdx.x;
  int lane = tid & 63;
  int w = tid >> 6;                 // wave id = M-tile
  const float* xb = x + (size_t)b * NC * LIN;

  for (int idx = tid; idx < NC * 71; idx += 256) {
    int c = idx / 71, o = idx % 71;
    int g = t0 + o;
    xs[c][o] = (g < LIN) ? xb[c * LIN + g] : 0.0f;
  }
  __syncthreads();

  int lrow = lane & 15;             // A row within M-tile / B col within N-tile
  int lgrp = lane >> 4;             // k-block (8 elems)

  f32x4 acc[8];
  #pragma unroll
  for (int n = 0; n < 8; ++n) acc[n] = (f32x4){0.f, 0.f, 0.f, 0.f};

  #pragma unroll
  for (int kb = 0; kb < 4; ++kb) {
    // Build A-frags: j = kb*32 + lgrp*8 + e  ->  c = kb*4 + lgrp, k-off = e
    int c = kb * 4 + lgrp;
    int tl = w * 16 + lrow;
    bf16x8 a_hi, a_lo;
    #pragma unroll
    for (int e = 0; e < 8; ++e) {
      float v = xs[c][tl + e];
      unsigned short h = f2bf(v);
      unsigned short l2 = f2bf(v - bf2f(h));
      a_hi[e] = (short)h;
      a_lo[e] = (short)l2;
    }
    #pragma unroll
    for (int n = 0; n < 8; ++n) {
      // B-frag: Q[i = n*16+lrow][j = kb*32 + lgrp*8 + e], e=0..7 contiguous
      int off = (n * 16 + lrow) * DD + kb * 32 + lgrp * 8;
      bf16x8 b_hi = *(const bf16x8*)(g_Qh + off);
      bf16x8 b_lo = *(const bf16x8*)(g_Ql + off);
      acc[n] = __builtin_amdgcn_mfma_f32_16x16x32_bf16(a_hi, b_hi, acc[n], 0, 0, 0);
      acc[n] = __builtin_amdgcn_mfma_f32_16x16x32_bf16(a_hi, b_lo, acc[n], 0, 0, 0);
      acc[n] = __builtin_amdgcn_mfma_f32_16x16x32_bf16(a_lo, b_hi, acc[n], 0, 0, 0);
    }
  }

  // Epilogue: per C-row r, lane holds U[t= w*16 + lgrp*4 + r][i= n*16+lrow].
  float pd[4] = {0.f, 0.f, 0.f, 0.f};
  float pn[4] = {0.f, 0.f, 0.f, 0.f};
  #pragma unroll
  for (int n = 0; n < 8; ++n) {
    int i = n * 16 + lrow;
    int cc = i >> 3, ko = i & 7;
    #pragma unroll
    for (int r = 0; r < 4; ++r) {
      int tl = w * 16 + lgrp * 4 + r;
      float v = xs[cc][tl + ko];
      pd[r] = fmaf(acc[n][r], v, pd[r]);
      pn[r] = fmaf(v, v, pn[r]);
    }
  }
  // reduce across the 16 lanes sharing (lgrp, r)
  #pragma unroll
  for (int r = 0; r < 4; ++r) {
    #pragma unroll
    for (int m = 1; m < 16; m <<= 1) {
      pd[r] += __shfl_xor(pd[r], m);
      pn[r] += __shfl_xor(pn[r], m);
    }
  }
  if (lrow == 0) {
    #pragma unroll
    for (int r = 0; r < 4; ++r) {
      int t = t0 + w * 16 + lgrp * 4 + r;
      if (t < LOUT) out[(size_t)b * LOUT + t] = pd[r] / (pn[r] + 1e-12f);
    }
  }
}

// ---------------------------------------------------------------------------

extern "C" void kernel_launch(void* const* d_in, const int* in_sizes, int n_in,
                              void* d_out, int out_size, void* d_ws, size_t ws_size,
                              hipStream_t stream) {
  const float* x     = (const float*)d_in[0];   // (16,16,4096) f32
  const float* E     = (const float*)d_in[1];   // (512,512)    f32
  const float* theta = (const float*)d_in[2];   // (3,9)        f32
  float* out = (float*)d_out;                   // (16,1,1,4089) f32
  (void)d_ws; (void)ws_size;

  w1_kernel<<<QDIM, 256, 0, stream>>>(E, theta);              // -> g_B
  mm_fused_kernel<<<QDIM, 256, 0, stream>>>(E, theta, 1, 0);  // g_B -> g_C
  mm_fused_kernel<<<QDIM, 256, 0, stream>>>(E, theta, 2, 1);  // g_C -> g_B
  formq_kernel<<<DD, 256, 0, stream>>>();                     // g_B -> g_Qh/g_Ql
  quad_mfma_kernel<<<dim3(NB, 64), 256, 0, stream>>>(x, out);
}